// Round 1
// baseline (1030.611 us; speedup 1.0000x reference)
//
#include <hip/hip_runtime.h>
#include <stdint.h>

// ISTA_Net fused MFMA implementation for gfx950.
// Shapes: M=1024, N=128, K=256, T=10, BATCH=8192. LAMBD=1.
// Inputs: y(8192,2,128) W(2,128,256) WX(2,256,128) E0(2,1024,256) etas(11) gammas(11)
// Outputs: x_T(2,8192,256) ++ loss_sparse ++ loss_eq/T ++ out_sparse  (4194307 floats)

typedef short s8v __attribute__((ext_vector_type(8)));   // 8 bf16 (4 VGPRs) MFMA operand
typedef short s4v __attribute__((ext_vector_type(4)));
typedef float f16v __attribute__((ext_vector_type(16))); // 32x32 MFMA accumulator

#define MFMA(a, b, c) __builtin_amdgcn_mfma_f32_32x32x16_bf16((a), (b), (c), 0, 0, 0)

__device__ __forceinline__ short f2bf(float f) {
  uint32_t u = __builtin_bit_cast(uint32_t, f);
  u = (u + 0x7FFFu + ((u >> 16) & 1u)) >> 16;   // RNE
  return (short)u;
}

// ---------------- prep kernels ----------------

__global__ void zero_tail(float* out) {
  if (threadIdx.x < 3) out[4194304 + threadIdx.x] = 0.f;
}

// C = WX * W (complex, 256x256). Store bf16 channels: [C0, C1, -C1]
__global__ void prep_C(const float* __restrict__ W, const float* __restrict__ WX,
                       short* __restrict__ Cb) {
  __shared__ float wx0[128], wx1[128];
  const int i = blockIdx.x, j = threadIdx.x;
  if (j < 128) { wx0[j] = WX[i * 128 + j]; wx1[j] = WX[32768 + i * 128 + j]; }
  __syncthreads();
  float c0 = 0.f, c1 = 0.f;
  for (int n = 0; n < 128; n++) {
    const float w0 = W[n * 256 + j], w1 = W[32768 + n * 256 + j];
    c0 += wx0[n] * w0 - wx1[n] * w1;
    c1 += wx0[n] * w1 + wx1[n] * w0;
  }
  Cb[i * 256 + j] = f2bf(c0);
  Cb[65536 + i * 256 + j] = f2bf(c1);
  Cb[131072 + i * 256 + j] = f2bf(-c1);
}

// WXb: bf16 copies [WX0, WX1], layout [ch][k=256][n=128]
__global__ void prep_WX(const float* __restrict__ WX, short* __restrict__ WXb) {
  const int t = blockIdx.x * 256 + threadIdx.x;   // 32768 threads
  WXb[t] = f2bf(WX[t]);
  WXb[32768 + t] = f2bf(WX[32768 + t]);
}

// E0b: [E0_re, -E0_im], layout [ch][m=1024][k=256]
__global__ void prep_E0(const float* __restrict__ E0, short* __restrict__ E0b) {
  const int t = blockIdx.x * 256 + threadIdx.x;   // 524288 threads
  const float v = E0[t];
  E0b[t] = f2bf(t >= 262144 ? -v : v);
}

// E0Tb: [E0_re^T, -E0_im^T], layout [ch][k=256][m=1024]
__global__ void prep_E0T(const float* __restrict__ E0, short* __restrict__ E0Tb) {
  __shared__ float tile[32][33];
  const int mb = blockIdx.x, kb = blockIdx.y, ch = blockIdx.z;
  const int tx = threadIdx.x & 31, ty = threadIdx.x >> 5;   // ty in [0,8)
  #pragma unroll
  for (int r = 0; r < 32; r += 8) {
    tile[ty + r][tx] = E0[ch * 262144 + (mb * 32 + ty + r) * 256 + kb * 32 + tx];
  }
  __syncthreads();
  const float sgn = ch ? -1.f : 1.f;
  #pragma unroll
  for (int r = 0; r < 32; r += 8) {
    E0Tb[ch * 262144 + (kb * 32 + ty + r) * 1024 + mb * 32 + tx] = f2bf(sgn * tile[tx][ty + r]);
  }
}

// ---------------- main fused kernel ----------------
// grid 256 (batch tile of 32), block 512 (8 waves).
// LDS: buf0 (32KB) = x bf16 [ch][bt][256] / aliased zs chunk [bt][512]
//      buf1 (32KB) = gx bf16 [ch][bt][256] / setup: y [3][bt][128]
// All LDS rows XOR-swizzled at 16B granules by (row&7).
// Register state per thread (C-layout, tile (ch, rt=w)): ndt (=-d~), xr (x), gx, xm.

__global__ __launch_bounds__(512, 2) void ista_main(
    const float* __restrict__ y,
    const float* __restrict__ etas,
    const float* __restrict__ gammas,
    const short* __restrict__ Cb,
    const short* __restrict__ WXb,
    const short* __restrict__ E0b,
    const short* __restrict__ E0Tb,
    float* __restrict__ out) {
  __shared__ short buf0[16384];
  __shared__ short buf1[16384];

  const int tid = threadIdx.x;
  const int w = tid >> 6;          // wave 0..7
  const int lane = tid & 63;
  const int l31 = lane & 31;
  const int h = lane >> 5;         // half-wave
  const int sw = l31 & 7;          // swizzle key
  const int b0 = blockIdx.x * 32;

  // ---- stage y -> buf1: [0]=y_re, [1]=y_im, [2]=-y_im (bf16, swizzled rows of 128)
  {
    const int bt = tid >> 4, j = tid & 15;
    const float* yb = y + (size_t)(b0 + bt) * 256;
    const int bsw = (bt & 7);
    #pragma unroll
    for (int rep = 0; rep < 2; rep++) {
      const int jj = j + rep * 16;
      const int ch = jj >> 4, n8 = (jj & 15) << 3;
      const float4 v0 = *(const float4*)(yb + ch * 128 + n8);
      const float4 v1 = *(const float4*)(yb + ch * 128 + n8 + 4);
      s8v pk;
      pk[0] = f2bf(v0.x); pk[1] = f2bf(v0.y); pk[2] = f2bf(v0.z); pk[3] = f2bf(v0.w);
      pk[4] = f2bf(v1.x); pk[5] = f2bf(v1.y); pk[6] = f2bf(v1.z); pk[7] = f2bf(v1.w);
      const int off = bt * 128 + (((n8 >> 3) ^ bsw) << 3);
      *(s8v*)(buf1 + ch * 4096 + off) = pk;
      if (ch == 1) {
        s8v nk;
        #pragma unroll
        for (int e = 0; e < 8; e++) nk[e] = pk[e] ^ (short)0x8000;
        *(s8v*)(buf1 + 8192 + off) = nk;
      }
    }
  }
  // ---- zero buf0 (x = 0)
  {
    s8v z = {0, 0, 0, 0, 0, 0, 0, 0};
    #pragma unroll
    for (int r = 0; r < 4; r++) *(s8v*)(buf0 + tid * 32 + r * 8) = z;
  }
  __syncthreads();

  // ---- d~ = WX * y^T (complex), accumulate in C-layout; keep ndt = -d~
  f16v ndt0, ndt1;
  {
    f16v ac0, ac1;
    #pragma unroll
    for (int r = 0; r < 16; r++) { ac0[r] = 0.f; ac1[r] = 0.f; }
    const int row = w * 32 + l31;
    #pragma unroll
    for (int kc = 0; kc < 8; kc++) {
      const s8v a0 = *(const s8v*)(WXb + row * 128 + kc * 16 + h * 8);
      const s8v a1 = *(const s8v*)(WXb + 32768 + row * 128 + kc * 16 + h * 8);
      const int yo = l31 * 128 + ((((kc * 2 + h)) ^ sw) << 3);
      const s8v by0 = *(const s8v*)(buf1 + yo);
      const s8v by1 = *(const s8v*)(buf1 + 4096 + yo);
      const s8v by1n = *(const s8v*)(buf1 + 8192 + yo);
      ac0 = MFMA(a0, by0, ac0);
      ac0 = MFMA(a1, by1n, ac0);
      ac1 = MFMA(a0, by1, ac1);
      ac1 = MFMA(a1, by0, ac1);
    }
    #pragma unroll
    for (int r = 0; r < 16; r++) { ndt0[r] = -ac0[r]; ndt1[r] = -ac1[r]; }
  }
  __syncthreads();   // buf1 (y) dead; becomes gx buffer

  f16v xr0, xr1;     // fp32 x state (C-layout)
  #pragma unroll
  for (int r = 0; r < 16; r++) { xr0[r] = 0.f; xr1[r] = 0.f; }
  float ls = 0.f, leq = 0.f, cntf = 0.f;

  #pragma unroll 1
  for (int it = 1; it <= 10; it++) {
    const float gam = gammas[it];
    const float eta = etas[it];

    // ---- Phase A: acc = C*x - d~ ; gx = x - gam*acc
    f16v ac0 = ndt0, ac1 = ndt1;
    {
      const int row = w * 32 + l31;
      #pragma unroll
      for (int kc = 0; kc < 16; kc++) {
        const s8v a0 = *(const s8v*)(Cb + row * 256 + kc * 16 + h * 8);
        const s8v a1 = *(const s8v*)(Cb + 65536 + row * 256 + kc * 16 + h * 8);
        const s8v a1n = *(const s8v*)(Cb + 131072 + row * 256 + kc * 16 + h * 8);
        const int xo = l31 * 256 + ((((kc * 2 + h)) ^ sw) << 3);
        const s8v bx0 = *(const s8v*)(buf0 + xo);
        const s8v bx1 = *(const s8v*)(buf0 + 8192 + xo);
        ac0 = MFMA(a0, bx0, ac0);
        ac0 = MFMA(a1n, bx1, ac0);
        ac1 = MFMA(a0, bx1, ac1);
        ac1 = MFMA(a1, bx0, ac1);
      }
    }
    f16v gx0, gx1;
    #pragma unroll
    for (int r = 0; r < 16; r++) {
      gx0[r] = xr0[r] - gam * ac0[r];
      gx1[r] = xr1[r] - gam * ac1[r];
    }
    // write gx (bf16) -> buf1
    #pragma unroll
    for (int r1 = 0; r1 < 4; r1++) {
      const int k0 = w * 32 + 8 * r1 + 4 * h;
      const int idx = l31 * 256 + (((k0 >> 3) ^ sw) << 3) + (k0 & 7);
      s4v p0, p1;
      #pragma unroll
      for (int r0 = 0; r0 < 4; r0++) {
        p0[r0] = f2bf(gx0[r1 * 4 + r0]);
        p1[r0] = f2bf(gx1[r1 * 4 + r0]);
      }
      *(s4v*)(buf1 + idx) = p0;
      *(s4v*)(buf1 + 8192 + idx) = p1;
    }
    __syncthreads();

    f16v xm0, xm1;
    #pragma unroll
    for (int r = 0; r < 16; r++) { xm0[r] = 0.f; xm1[r] = 0.f; }

    #pragma unroll 1
    for (int c = 0; c < 2; c++) {
      // ---- Phase B: z = Re(E0 * gx) for m in [c*512, c*512+512); 2 m-tiles/wave
      f16v z1, z2;
      #pragma unroll
      for (int r = 0; r < 16; r++) { z1[r] = 0.f; z2[r] = 0.f; }
      {
        const int m1 = (c * 16 + w) * 32 + l31;
        const int m2 = m1 + 256;
        #pragma unroll
        for (int kc = 0; kc < 16; kc++) {
          const int ka = kc * 16 + h * 8;
          const s8v aE01 = *(const s8v*)(E0b + m1 * 256 + ka);
          const s8v aE11 = *(const s8v*)(E0b + 262144 + m1 * 256 + ka);
          const s8v aE02 = *(const s8v*)(E0b + m2 * 256 + ka);
          const s8v aE12 = *(const s8v*)(E0b + 262144 + m2 * 256 + ka);
          const int xo = l31 * 256 + ((((kc * 2 + h)) ^ sw) << 3);
          const s8v bg0 = *(const s8v*)(buf1 + xo);
          const s8v bg1 = *(const s8v*)(buf1 + 8192 + xo);
          z1 = MFMA(aE01, bg0, z1);
          z1 = MFMA(aE11, bg1, z1);
          z2 = MFMA(aE02, bg0, z2);
          z2 = MFMA(aE12, bg1, z2);
        }
      }
      // shrink + losses + write zs chunk -> buf0 [bt][512]
      #pragma unroll
      for (int half = 0; half < 2; half++) {
        const int rtl = w + half * 8;
        #pragma unroll
        for (int r1 = 0; r1 < 4; r1++) {
          s4v ps;
          #pragma unroll
          for (int r0 = 0; r0 < 4; r0++) {
            const float v = half ? z2[r1 * 4 + r0] : z1[r1 * 4 + r0];
            const float av = fabsf(v) - eta;
            float s = 0.f;
            if (av > 0.f) {
              s = (v > 0.f) ? av : -av;
              ls += av;
              if (it == 10 && av > 1e-3f) cntf += 1.f;
            }
            ps[r0] = f2bf(s);
          }
          const int ml = rtl * 32 + 8 * r1 + 4 * h;
          *(s4v*)(buf0 + l31 * 512 + (((ml >> 3) ^ sw) << 3) + (ml & 7)) = ps;
        }
      }
      __syncthreads();

      // ---- Phase C: xm += [E0_re^T; -E0_im^T] * s  (reduce over this chunk's 512 m's)
      {
        const int row = w * 32 + l31;
        #pragma unroll
        for (int kc = 0; kc < 32; kc++) {
          const int mcol = c * 512 + kc * 16 + h * 8;
          const s8v aT0 = *(const s8v*)(E0Tb + row * 1024 + mcol);
          const s8v aT1 = *(const s8v*)(E0Tb + 262144 + row * 1024 + mcol);
          const int zo = l31 * 512 + ((((kc * 2 + h)) ^ sw) << 3);
          const s8v bz = *(const s8v*)(buf0 + zo);
          xm0 = MFMA(aT0, bz, xm0);
          xm1 = MFMA(aT1, bz, xm1);
        }
      }
      __syncthreads();
    }

    // ---- Phase D: huber(gx, xm); x = xm; write x (bf16) -> buf0
    #pragma unroll
    for (int r = 0; r < 16; r++) {
      const float d0 = gx0[r] - xm0[r];
      const float d1 = gx1[r] - xm1[r];
      const float a0 = fabsf(d0), a1 = fabsf(d1);
      leq += (a0 < 1.f) ? 0.5f * d0 * d0 : (a0 - 0.5f);
      leq += (a1 < 1.f) ? 0.5f * d1 * d1 : (a1 - 0.5f);
      xr0[r] = xm0[r];
      xr1[r] = xm1[r];
    }
    #pragma unroll
    for (int r1 = 0; r1 < 4; r1++) {
      const int k0 = w * 32 + 8 * r1 + 4 * h;
      const int idx = l31 * 256 + (((k0 >> 3) ^ sw) << 3) + (k0 & 7);
      s4v p0, p1;
      #pragma unroll
      for (int r0 = 0; r0 < 4; r0++) {
        p0[r0] = f2bf(xr0[r1 * 4 + r0]);
        p1[r0] = f2bf(xr1[r1 * 4 + r0]);
      }
      *(s4v*)(buf0 + idx) = p0;
      *(s4v*)(buf0 + 8192 + idx) = p1;
    }
    __syncthreads();
  }

  // ---- write x_T (2, 8192, 256) fp32
  {
    const size_t ob = (size_t)(b0 + l31) * 256;
    #pragma unroll
    for (int r1 = 0; r1 < 4; r1++) {
      const int k0 = w * 32 + 8 * r1 + 4 * h;
      float4 v0, v1;
      v0.x = xr0[r1 * 4 + 0]; v0.y = xr0[r1 * 4 + 1]; v0.z = xr0[r1 * 4 + 2]; v0.w = xr0[r1 * 4 + 3];
      v1.x = xr1[r1 * 4 + 0]; v1.y = xr1[r1 * 4 + 1]; v1.z = xr1[r1 * 4 + 2]; v1.w = xr1[r1 * 4 + 3];
      *(float4*)(out + ob + k0) = v0;
      *(float4*)(out + 2097152 + ob + k0) = v1;
    }
  }
  // ---- scalar reductions
  #pragma unroll
  for (int off = 32; off > 0; off >>= 1) {
    ls += __shfl_down(ls, off);
    leq += __shfl_down(leq, off);
    cntf += __shfl_down(cntf, off);
  }
  if (lane == 0) {
    atomicAdd(out + 4194304, ls * (1.f / 8192.f));
    atomicAdd(out + 4194305, leq * (1.f / (2.f * 256.f * 8192.f * 10.f)));
    atomicAdd(out + 4194306, cntf * (1.f / 8192.f));
  }
}

extern "C" void kernel_launch(void* const* d_in, const int* in_sizes, int n_in,
                              void* d_out, int out_size, void* d_ws, size_t ws_size,
                              hipStream_t stream) {
  (void)in_sizes; (void)n_in; (void)out_size; (void)ws_size;
  const float* y = (const float*)d_in[0];
  const float* W = (const float*)d_in[1];
  const float* WX = (const float*)d_in[2];
  const float* E0 = (const float*)d_in[3];
  const float* etas = (const float*)d_in[4];
  const float* gammas = (const float*)d_in[5];
  float* out = (float*)d_out;

  short* Cb = (short*)d_ws;            // 3 * 65536
  short* WXb = Cb + 196608;            // 2 * 32768
  short* E0b = WXb + 65536;            // 2 * 262144
  short* E0Tb = E0b + 524288;          // 2 * 262144  (total ~2.6 MB)

  zero_tail<<<1, 64, 0, stream>>>(out);
  prep_C<<<256, 256, 0, stream>>>(W, WX, Cb);
  prep_WX<<<128, 256, 0, stream>>>(WX, WXb);
  prep_E0<<<2048, 256, 0, stream>>>(E0, E0b);
  prep_E0T<<<dim3(32, 8, 2), 256, 0, stream>>>(E0, E0Tb);
  ista_main<<<256, 512, 0, stream>>>(y, etas, gammas, Cb, WXb, E0b, E0Tb, out);
}